// Round 1
// 425.327 us; speedup vs baseline: 1.1732x; 1.1732x over previous
//
#include <hip/hip_runtime.h>
#include <math.h>

// Problem: contrastive loss over 2048 sequences.
// rep: (2048, 64, 512) f32; lens: (2048,) i32; W: (256, 512) f32; b: (256,) f32
// loss = mean_i [ lse_{k != i}(20 * z_i . z_k) - 20 * z_i . z_{partner(i)} ]
// where z = normalize(gather(rep, lens-1) @ W^T + b), partner(i) = (i + 1024) % 2048.

#define NROWS 2048
#define DDIM  512
#define PDIM  256
static constexpr float INV_T = 20.0f;   // 1 / 0.05
static constexpr float EPSN  = 1e-8f;

// ---------------------------------------------------------------------------
// Kernel 1: gather last valid token, project (x @ W^T + b), L2-normalize.
// 512 blocks x 4 rows (2 blocks/CU for TLP; old version was 1 block/CU).
// Thread t owns output column p = t. W staged via float4 (old: scalar loads).
// ---------------------------------------------------------------------------
__global__ __launch_bounds__(256) void k_proj(const float* __restrict__ rep,
                                              const int*   __restrict__ lens,
                                              const float* __restrict__ W,
                                              const float* __restrict__ bias,
                                              float* __restrict__ z) {
  __shared__ float A[4][512];      // 8 KB gathered input rows
  __shared__ float Wl[32][257];    // ~32.9 KB W chunk, [d][p], pad 257 -> conflict-free
  __shared__ float red[4][4];      // total ~41.2 KB -> 2 blocks/CU co-resident

  const int t   = threadIdx.x;
  const int blk = blockIdx.x;      // rows blk*4 .. blk*4+3

  // Gather 4 rows (float4, coalesced).
  for (int i = 0; i < 2; ++i) {
    int e = i * 256 + t;           // 0..511 over 4 rows x 128 float4
    int r = e >> 7;
    int q = e & 127;
    int n = blk * 4 + r;
    int idx = lens[n] - 1;
    idx = idx < 0 ? 0 : (idx > 63 ? 63 : idx);
    const float4* src = (const float4*)(rep + ((size_t)(n * 64 + idx)) * 512);
    ((float4*)&A[r][0])[q] = src[q];
  }

  const int p = t;
  float acc[4];
  {
    float bv = bias[p];
    for (int r = 0; r < 4; ++r) acc[r] = bv;
  }

  const float4* W4 = (const float4*)W;
  for (int kc = 0; kc < DDIM; kc += 32) {
    __syncthreads();       // prev compute done (and first: gather done)
    // Stage W[0:256][kc:kc+32] into Wl[d][p]: 2048 float4, 256 threads -> 8 each.
    // 8 consecutive lanes read 8 consecutive float4 (128B) -> coalesced.
    for (int i = 0; i < 8; ++i) {
      int idx = i * 256 + t;       // 0..2047
      int pp = idx >> 3;           // 0..255 (W row / output col)
      int dq = idx & 7;            // float4 index within 32-wide d chunk
      float4 w = W4[(size_t)pp * 128 + (kc >> 2) + dq];
      Wl[dq * 4 + 0][pp] = w.x;    // banks (4*dq+j + pp) % 32: <=2-way, free
      Wl[dq * 4 + 1][pp] = w.y;
      Wl[dq * 4 + 2][pp] = w.z;
      Wl[dq * 4 + 3][pp] = w.w;
    }
    __syncthreads();
    for (int d4 = 0; d4 < 8; ++d4) {
      float w0 = Wl[d4 * 4 + 0][p];   // stride-257 rows: bank (d+p)%32, conflict-free
      float w1 = Wl[d4 * 4 + 1][p];
      float w2 = Wl[d4 * 4 + 2][p];
      float w3 = Wl[d4 * 4 + 3][p];
      for (int r = 0; r < 4; ++r) {
        float4 av = *(const float4*)&A[r][kc + d4 * 4];  // broadcast read
        acc[r] += av.x * w0 + av.y * w1 + av.z * w2 + av.w * w3;
      }
    }
  }

  // Per-row sum of squares: wave shuffle + cross-wave LDS.
  const int wid = t >> 6, lane = t & 63;
  for (int r = 0; r < 4; ++r) {
    float v = acc[r] * acc[r];
    for (int off = 32; off >= 1; off >>= 1) v += __shfl_xor(v, off, 64);
    if (lane == 0) red[r][wid] = v;
  }
  __syncthreads();
  for (int r = 0; r < 4; ++r) {
    float ss = red[r][0] + red[r][1] + red[r][2] + red[r][3];
    float nrm = sqrtf(ss);
    nrm = nrm < EPSN ? EPSN : nrm;
    z[(size_t)(blk * 4 + r) * 256 + p] = acc[r] / nrm;
  }
}

// ---------------------------------------------------------------------------
// Kernel 2: SYMMETRIC 64x64 Gram tiles (upper triangle incl. diagonal, 528
// blocks). Each off-diagonal tile (I<J) emits:
//   row-stats  : rows of block I over cols of block J -> slot (row, J)
//   col-stats  : rows of block J over cols of block I -> slot (col, I)
// Diagonal tiles emit row-stats only (diag masked to -inf).
// Every (row, col-block) partial slot is written exactly once.
// Staging now float4 (was scalar); stats logic unchanged (verified, absmax 0).
// ---------------------------------------------------------------------------
__global__ __launch_bounds__(256) void k_gram(const float* __restrict__ z,
                                              float* __restrict__ mPart,
                                              float* __restrict__ sPart) {
  __shared__ float Zr[64][36];   // pad 36: float4-aligned, <=2-way banks (free)
  __shared__ float Zc[64][36];
  __shared__ float cred[2][4][16][4];  // [phase][wave][tx][ci]

  const int t = threadIdx.x;
  // Decode upper-triangle tile index: row I has (32 - I) tiles.
  int b = blockIdx.x;
  int I = 0;
  while (b >= 32 - I) { b -= 32 - I; ++I; }
  const int J = I + b;
  const int rb = I * 64;
  const int cb = J * 64;
  const int tx = t & 15, ty = t >> 4;
  const int wv = t >> 6;

  float acc[4][4];
  for (int i = 0; i < 4; ++i)
    for (int j = 0; j < 4; ++j) acc[i][j] = 0.0f;

  const float4* z4 = (const float4*)z;
  for (int kc = 0; kc < PDIM; kc += 32) {
    __syncthreads();
    // 512 float4 per buffer, 256 threads -> 2 each, 8 consecutive lanes
    // read 8 consecutive float4 of one z row (128B, coalesced).
    for (int i = 0; i < 2; ++i) {
      int idx = i * 256 + t;       // 0..511
      int row = idx >> 3;          // 0..63
      int dq  = idx & 7;           // float4 within 32-wide chunk
      *(float4*)&Zr[row][dq * 4] = z4[(size_t)(rb + row) * 64 + (kc >> 2) + dq];
      *(float4*)&Zc[row][dq * 4] = z4[(size_t)(cb + row) * 64 + (kc >> 2) + dq];
    }
    __syncthreads();
    for (int d4 = 0; d4 < 32; d4 += 4) {
      float4 a0 = *(const float4*)&Zr[ty +  0][d4];
      float4 a1 = *(const float4*)&Zr[ty + 16][d4];
      float4 a2 = *(const float4*)&Zr[ty + 32][d4];
      float4 a3 = *(const float4*)&Zr[ty + 48][d4];
      float4 b0 = *(const float4*)&Zc[tx +  0][d4];
      float4 b1 = *(const float4*)&Zc[tx + 16][d4];
      float4 b2 = *(const float4*)&Zc[tx + 32][d4];
      float4 b3 = *(const float4*)&Zc[tx + 48][d4];
#define DOT4(u, v) (u.x * v.x + u.y * v.y + u.z * v.z + u.w * v.w)
      acc[0][0] += DOT4(a0, b0); acc[0][1] += DOT4(a0, b1);
      acc[0][2] += DOT4(a0, b2); acc[0][3] += DOT4(a0, b3);
      acc[1][0] += DOT4(a1, b0); acc[1][1] += DOT4(a1, b1);
      acc[1][2] += DOT4(a1, b2); acc[1][3] += DOT4(a1, b3);
      acc[2][0] += DOT4(a2, b0); acc[2][1] += DOT4(a2, b1);
      acc[2][2] += DOT4(a2, b2); acc[2][3] += DOT4(a2, b3);
      acc[3][0] += DOT4(a3, b0); acc[3][1] += DOT4(a3, b1);
      acc[3][2] += DOT4(a3, b2); acc[3][3] += DOT4(a3, b3);
#undef DOT4
    }
  }

  // Masked, temperature-scaled logit values (diag only possible when I==J).
  float v[4][4];
  for (int ri = 0; ri < 4; ++ri) {
    const int grow = rb + ty + 16 * ri;
    for (int ci = 0; ci < 4; ++ci) {
      const int gcol = cb + tx + 16 * ci;
      v[ri][ci] = (grow == gcol) ? -INFINITY : acc[ri][ci] * INV_T;
    }
  }

  // ---- Row stats (rows of block I over this tile's 64 cols) -> slot (row, J)
  for (int ri = 0; ri < 4; ++ri) {
    const int grow = rb + ty + 16 * ri;
    float m = -INFINITY;
    for (int ci = 0; ci < 4; ++ci) m = fmaxf(m, v[ri][ci]);
    for (int off = 1; off < 16; off <<= 1) m = fmaxf(m, __shfl_xor(m, off, 64));
    float s = 0.0f;
    for (int ci = 0; ci < 4; ++ci)
      s += (v[ri][ci] == -INFINITY) ? 0.0f : __expf(v[ri][ci] - m);
    for (int off = 1; off < 16; off <<= 1) s += __shfl_xor(s, off, 64);
    if (tx == 0) {
      mPart[(size_t)grow * 32 + J] = m;
      sPart[(size_t)grow * 32 + J] = s;
    }
  }

  // ---- Col stats (rows of block J over cols of block I) -> slot (col, I)
  if (I != J) {
    // Phase 1: column max over the 64 rows.
    float cm[4];
    for (int ci = 0; ci < 4; ++ci) {
      float m = v[0][ci];
      for (int ri = 1; ri < 4; ++ri) m = fmaxf(m, v[ri][ci]);
      m = fmaxf(m, __shfl_xor(m, 16, 64));   // reduce over ty within wave
      m = fmaxf(m, __shfl_xor(m, 32, 64));
      cm[ci] = m;
    }
    if ((t & 48) == 0)                        // one ty-representative per wave
      for (int ci = 0; ci < 4; ++ci) cred[0][wv][tx][ci] = cm[ci];
    __syncthreads();
    float M[4];
    for (int ci = 0; ci < 4; ++ci) {
      float m = cred[0][0][tx][ci];
      for (int w = 1; w < 4; ++w) m = fmaxf(m, cred[0][w][tx][ci]);
      M[ci] = m;
    }
    // Phase 2: column sum of exp.
    float cs[4];
    for (int ci = 0; ci < 4; ++ci) {
      float s = 0.0f;
      for (int ri = 0; ri < 4; ++ri) s += __expf(v[ri][ci] - M[ci]);
      s += __shfl_xor(s, 16, 64);
      s += __shfl_xor(s, 32, 64);
      cs[ci] = s;
    }
    if ((t & 48) == 0)
      for (int ci = 0; ci < 4; ++ci) cred[1][wv][tx][ci] = cs[ci];
    __syncthreads();
    if (t < 16) {                             // ty == 0 threads write 64 cols
      for (int ci = 0; ci < 4; ++ci) {
        float s = cred[1][0][tx][ci] + cred[1][1][tx][ci] +
                  cred[1][2][tx][ci] + cred[1][3][tx][ci];
        const int gcol = cb + tx + 16 * ci;
        mPart[(size_t)gcol * 32 + I] = M[ci];
        sPart[(size_t)gcol * 32 + I] = s;
      }
    }
  }
}

// ---------------------------------------------------------------------------
// Kernel 3: combine 32 partials per row -> lse; positive dot; mean via atomic.
// One wave per row (4 rows / block). Block-level LDS reduce first so only
// ONE same-address atomic per block (512 total, was 2048 -> less L2 serialization).
// ---------------------------------------------------------------------------
__global__ __launch_bounds__(256) void k_finish(const float* __restrict__ z,
                                                const float* __restrict__ mPart,
                                                const float* __restrict__ sPart,
                                                float* __restrict__ out) {
  __shared__ float red[4];
  const int t = threadIdx.x;
  const int wid = t >> 6, lane = t & 63;
  const int row = blockIdx.x * 4 + wid;

  float m = (lane < 32) ? mPart[(size_t)row * 32 + lane] : -INFINITY;
  float s = (lane < 32) ? sPart[(size_t)row * 32 + lane] : 0.0f;
  float M = m;
  for (int off = 1; off < 64; off <<= 1) M = fmaxf(M, __shfl_xor(M, off, 64));
  float se = (lane < 32) ? s * __expf(m - M) : 0.0f;
  for (int off = 1; off < 64; off <<= 1) se += __shfl_xor(se, off, 64);
  float lse = M + logf(se);

  const int partner = row < 1024 ? row + 1024 : row - 1024;
  float4 a = ((const float4*)(z + (size_t)row * 256))[lane];
  float4 b = ((const float4*)(z + (size_t)partner * 256))[lane];
  float d = a.x * b.x + a.y * b.y + a.z * b.z + a.w * b.w;
  for (int off = 1; off < 64; off <<= 1) d += __shfl_xor(d, off, 64);

  if (lane == 0) red[wid] = lse - d * INV_T;
  __syncthreads();
  if (t == 0)
    atomicAdd(out, (red[0] + red[1] + red[2] + red[3]) * (1.0f / 2048.0f));
}

// ---------------------------------------------------------------------------
extern "C" void kernel_launch(void* const* d_in, const int* in_sizes, int n_in,
                              void* d_out, int out_size, void* d_ws, size_t ws_size,
                              hipStream_t stream) {
  const float* rep  = (const float*)d_in[0];
  const int*   lens = (const int*)  d_in[1];
  const float* W    = (const float*)d_in[2];
  const float* bias = (const float*)d_in[3];
  float* out = (float*)d_out;

  float* z     = (float*)d_ws;            // 2048*256 f32 = 2 MB
  float* mPart = z + NROWS * PDIM;        // 2048*32 f32
  float* sPart = mPart + NROWS * 32;      // 2048*32 f32

  hipMemsetAsync(d_out, 0, sizeof(float), stream);
  k_proj  <<<512, 256, 0, stream>>>(rep, lens, W, bias, z);
  k_gram  <<<528, 256, 0, stream>>>(z, mPart, sPart);
  k_finish<<<512, 256, 0, stream>>>(z, mPart, sPart, out);
}

// Round 2
// 380.071 us; speedup vs baseline: 1.3129x; 1.1191x over previous
//
#include <hip/hip_runtime.h>
#include <math.h>

// Problem: contrastive loss over 2048 sequences.
// rep: (2048, 64, 512) f32; lens: (2048,) i32; W: (256, 512) f32; b: (256,) f32
// loss = mean_i [ lse_{k != i}(20 * z_i . z_k) - 20 * z_i . z_{partner(i)} ]
// where z = normalize(gather(rep, lens-1) @ W^T + b), partner(i) = (i + 1024) % 2048.

#define NROWS 2048
#define DDIM  512
#define PDIM  256
static constexpr float INV_T = 20.0f;   // 1 / 0.05
static constexpr float EPSN  = 1e-8f;

// ---------------------------------------------------------------------------
// Kernel 1: gather last valid token, project (x @ W^T + b), L2-normalize.
// 256 blocks x 512 threads x 8 rows: halves W L2 re-read traffic vs 512x256x4
// (128 MB vs 256 MB). Thread t owns output col p = t&255, rows (t>>8)*4..+3.
// W chunk is register-prefetched one phase ahead (T14 issue-early/write-late):
// the global-load latency hides under the previous chunk's FMA phase, so the
// staging barrier no longer stalls on vmcnt.
// Also zeroes out[0] (replaces the hipMemsetAsync dispatch).
// ---------------------------------------------------------------------------
__global__ __launch_bounds__(512) void k_proj(const float* __restrict__ rep,
                                              const int*   __restrict__ lens,
                                              const float* __restrict__ W,
                                              const float* __restrict__ bias,
                                              float* __restrict__ z,
                                              float* __restrict__ out) {
  __shared__ float A[8][512];      // 16 KB gathered input rows
  __shared__ float Wl[32][257];    // ~32.9 KB W chunk, [d][p], pad 257 -> conflict-free
  __shared__ float red[8][4];      // total ~49.4 KB

  const int t   = threadIdx.x;     // 0..511
  const int blk = blockIdx.x;      // rows blk*8 .. blk*8+7

  if (blk == 0 && t == 0) out[0] = 0.0f;   // stream-ordered before k_finish atomics

  // Gather 8 rows (1024 float4, 2 per thread, coalesced).
  for (int i = 0; i < 2; ++i) {
    int e = i * 512 + t;
    int r = e >> 7;
    int q = e & 127;
    int n = blk * 8 + r;
    int idx = lens[n] - 1;
    idx = idx < 0 ? 0 : (idx > 63 ? 63 : idx);
    const float4* src = (const float4*)(rep + ((size_t)(n * 64 + idx)) * 512);
    ((float4*)&A[r][0])[q] = src[q];
  }

  const int p    = t & 255;
  const int half = t >> 8;         // 0..1 -> owns rows half*4 .. half*4+3

  float acc[4];
  {
    float bv = bias[p];
    for (int r = 0; r < 4; ++r) acc[r] = bv;
  }

  // W staging geometry: chunk [256][32] = 2048 float4; 512 threads -> 4 each.
  // 8 consecutive lanes read 8 consecutive float4 of one W row (128B, coalesced).
  const float4* W4 = (const float4*)W;
  int pp[4], dq[4];
  for (int i = 0; i < 4; ++i) {
    int idx = i * 512 + t;
    pp[i] = idx >> 3;              // W row / output col
    dq[i] = idx & 7;               // float4 index within 32-wide d chunk
  }

  float4 wreg[4];
  // Prologue: prefetch chunk 0 into regs.
  for (int i = 0; i < 4; ++i)
    wreg[i] = W4[(size_t)pp[i] * 128 + dq[i]];
  __syncthreads();                 // gather stores to A complete
  for (int i = 0; i < 4; ++i) {    // write chunk 0 (banks (4dq+j+pp)%32 -> ~2-way, free)
    Wl[dq[i] * 4 + 0][pp[i]] = wreg[i].x;
    Wl[dq[i] * 4 + 1][pp[i]] = wreg[i].y;
    Wl[dq[i] * 4 + 2][pp[i]] = wreg[i].z;
    Wl[dq[i] * 4 + 3][pp[i]] = wreg[i].w;
  }
  __syncthreads();

  for (int kc = 0; kc < DDIM; kc += 32) {
    const bool more = (kc + 32) < DDIM;
    if (more) {                    // issue next-chunk loads BEFORE compute
      int kq = (kc + 32) >> 2;
      for (int i = 0; i < 4; ++i)
        wreg[i] = W4[(size_t)pp[i] * 128 + kq + dq[i]];
    }
    for (int d4 = 0; d4 < 8; ++d4) {
      float w0 = Wl[d4 * 4 + 0][p];   // stride-257: bank (d+p)%32, conflict-free
      float w1 = Wl[d4 * 4 + 1][p];
      float w2 = Wl[d4 * 4 + 2][p];
      float w3 = Wl[d4 * 4 + 3][p];
      for (int r = 0; r < 4; ++r) {
        float4 av = *(const float4*)&A[half * 4 + r][kc + d4 * 4];  // broadcast
        acc[r] += av.x * w0 + av.y * w1 + av.z * w2 + av.w * w3;
      }
    }
    if (more) {
      __syncthreads();             // all reads of current Wl done
      for (int i = 0; i < 4; ++i) {
        Wl[dq[i] * 4 + 0][pp[i]] = wreg[i].x;
        Wl[dq[i] * 4 + 1][pp[i]] = wreg[i].y;
        Wl[dq[i] * 4 + 2][pp[i]] = wreg[i].z;
        Wl[dq[i] * 4 + 3][pp[i]] = wreg[i].w;
      }
      __syncthreads();
    }
  }

  // Per-row sum of squares: 4 waves own each row-half.
  const int wid = t >> 6, lane = t & 63;   // wid 0..7; wid<4 <-> half==0
  for (int r = 0; r < 4; ++r) {
    float v = acc[r] * acc[r];
    for (int off = 32; off >= 1; off >>= 1) v += __shfl_xor(v, off, 64);
    if (lane == 0) red[half * 4 + r][wid & 3] = v;
  }
  __syncthreads();
  for (int r = 0; r < 4; ++r) {
    const int grow = half * 4 + r;
    float ss = red[grow][0] + red[grow][1] + red[grow][2] + red[grow][3];
    float nrm = sqrtf(ss);
    nrm = nrm < EPSN ? EPSN : nrm;
    z[(size_t)(blk * 8 + grow) * 256 + p] = acc[r] / nrm;
  }
}

// ---------------------------------------------------------------------------
// Kernel 2: SYMMETRIC 64x64 Gram tiles (upper triangle incl. diagonal, 528
// blocks). Off-diagonal tile (I<J) emits row-stats (slot (row,J)) and
// col-stats (slot (col,I)); diagonal tiles emit row-stats only (diag -inf).
// Every (row, col-block) partial slot is written exactly once.
// Zr/Zc chunks now register-prefetched one phase ahead (stats code unchanged,
// verified absmax 0).
// ---------------------------------------------------------------------------
__global__ __launch_bounds__(256) void k_gram(const float* __restrict__ z,
                                              float* __restrict__ mPart,
                                              float* __restrict__ sPart) {
  __shared__ float Zr[64][36];   // pad 36: float4-aligned, <=2-way banks (free)
  __shared__ float Zc[64][36];
  __shared__ float cred[2][4][16][4];  // [phase][wave][tx][ci]

  const int t = threadIdx.x;
  // Decode upper-triangle tile index: row I has (32 - I) tiles.
  int b = blockIdx.x;
  int I = 0;
  while (b >= 32 - I) { b -= 32 - I; ++I; }
  const int J = I + b;
  const int rb = I * 64;
  const int cb = J * 64;
  const int tx = t & 15, ty = t >> 4;
  const int wv = t >> 6;

  float acc[4][4];
  for (int i = 0; i < 4; ++i)
    for (int j = 0; j < 4; ++j) acc[i][j] = 0.0f;

  // Staging geometry: 512 float4 per buffer per chunk, 256 threads -> 2 each.
  const float4* z4 = (const float4*)z;
  int srow[2], sdq[2];
  for (int i = 0; i < 2; ++i) {
    int idx = i * 256 + t;
    srow[i] = idx >> 3;            // 0..63
    sdq[i]  = idx & 7;             // float4 within 32-wide chunk
  }

  float4 rreg[2], creg[2];
  // Prologue: prefetch + write chunk 0.
  for (int i = 0; i < 2; ++i) {
    rreg[i] = z4[(size_t)(rb + srow[i]) * 64 + sdq[i]];
    creg[i] = z4[(size_t)(cb + srow[i]) * 64 + sdq[i]];
  }
  for (int i = 0; i < 2; ++i) {
    *(float4*)&Zr[srow[i]][sdq[i] * 4] = rreg[i];
    *(float4*)&Zc[srow[i]][sdq[i] * 4] = creg[i];
  }
  __syncthreads();

  for (int kc = 0; kc < PDIM; kc += 32) {
    const bool more = (kc + 32) < PDIM;
    if (more) {                    // issue next-chunk loads BEFORE compute
      int kq = (kc + 32) >> 2;
      for (int i = 0; i < 2; ++i) {
        rreg[i] = z4[(size_t)(rb + srow[i]) * 64 + kq + sdq[i]];
        creg[i] = z4[(size_t)(cb + srow[i]) * 64 + kq + sdq[i]];
      }
    }
    for (int d4 = 0; d4 < 32; d4 += 4) {
      float4 a0 = *(const float4*)&Zr[ty +  0][d4];
      float4 a1 = *(const float4*)&Zr[ty + 16][d4];
      float4 a2 = *(const float4*)&Zr[ty + 32][d4];
      float4 a3 = *(const float4*)&Zr[ty + 48][d4];
      float4 b0 = *(const float4*)&Zc[tx +  0][d4];
      float4 b1 = *(const float4*)&Zc[tx + 16][d4];
      float4 b2 = *(const float4*)&Zc[tx + 32][d4];
      float4 b3 = *(const float4*)&Zc[tx + 48][d4];
#define DOT4(u, v) (u.x * v.x + u.y * v.y + u.z * v.z + u.w * v.w)
      acc[0][0] += DOT4(a0, b0); acc[0][1] += DOT4(a0, b1);
      acc[0][2] += DOT4(a0, b2); acc[0][3] += DOT4(a0, b3);
      acc[1][0] += DOT4(a1, b0); acc[1][1] += DOT4(a1, b1);
      acc[1][2] += DOT4(a1, b2); acc[1][3] += DOT4(a1, b3);
      acc[2][0] += DOT4(a2, b0); acc[2][1] += DOT4(a2, b1);
      acc[2][2] += DOT4(a2, b2); acc[2][3] += DOT4(a2, b3);
      acc[3][0] += DOT4(a3, b0); acc[3][1] += DOT4(a3, b1);
      acc[3][2] += DOT4(a3, b2); acc[3][3] += DOT4(a3, b3);
#undef DOT4
    }
    if (more) {
      __syncthreads();             // all reads of current chunk done
      for (int i = 0; i < 2; ++i) {
        *(float4*)&Zr[srow[i]][sdq[i] * 4] = rreg[i];
        *(float4*)&Zc[srow[i]][sdq[i] * 4] = creg[i];
      }
      __syncthreads();
    }
  }

  // Masked, temperature-scaled logit values (diag only possible when I==J).
  float v[4][4];
  for (int ri = 0; ri < 4; ++ri) {
    const int grow = rb + ty + 16 * ri;
    for (int ci = 0; ci < 4; ++ci) {
      const int gcol = cb + tx + 16 * ci;
      v[ri][ci] = (grow == gcol) ? -INFINITY : acc[ri][ci] * INV_T;
    }
  }

  // ---- Row stats (rows of block I over this tile's 64 cols) -> slot (row, J)
  for (int ri = 0; ri < 4; ++ri) {
    const int grow = rb + ty + 16 * ri;
    float m = -INFINITY;
    for (int ci = 0; ci < 4; ++ci) m = fmaxf(m, v[ri][ci]);
    for (int off = 1; off < 16; off <<= 1) m = fmaxf(m, __shfl_xor(m, off, 64));
    float s = 0.0f;
    for (int ci = 0; ci < 4; ++ci)
      s += (v[ri][ci] == -INFINITY) ? 0.0f : __expf(v[ri][ci] - m);
    for (int off = 1; off < 16; off <<= 1) s += __shfl_xor(s, off, 64);
    if (tx == 0) {
      mPart[(size_t)grow * 32 + J] = m;
      sPart[(size_t)grow * 32 + J] = s;
    }
  }

  // ---- Col stats (rows of block J over cols of block I) -> slot (col, I)
  if (I != J) {
    // Phase 1: column max over the 64 rows.
    float cm[4];
    for (int ci = 0; ci < 4; ++ci) {
      float m = v[0][ci];
      for (int ri = 1; ri < 4; ++ri) m = fmaxf(m, v[ri][ci]);
      m = fmaxf(m, __shfl_xor(m, 16, 64));   // reduce over ty within wave
      m = fmaxf(m, __shfl_xor(m, 32, 64));
      cm[ci] = m;
    }
    if ((t & 48) == 0)                        // one ty-representative per wave
      for (int ci = 0; ci < 4; ++ci) cred[0][wv][tx][ci] = cm[ci];
    __syncthreads();
    float M[4];
    for (int ci = 0; ci < 4; ++ci) {
      float m = cred[0][0][tx][ci];
      for (int w = 1; w < 4; ++w) m = fmaxf(m, cred[0][w][tx][ci]);
      M[ci] = m;
    }
    // Phase 2: column sum of exp.
    float cs[4];
    for (int ci = 0; ci < 4; ++ci) {
      float s = 0.0f;
      for (int ri = 0; ri < 4; ++ri) s += __expf(v[ri][ci] - M[ci]);
      s += __shfl_xor(s, 16, 64);
      s += __shfl_xor(s, 32, 64);
      cs[ci] = s;
    }
    if ((t & 48) == 0)
      for (int ci = 0; ci < 4; ++ci) cred[1][wv][tx][ci] = cs[ci];
    __syncthreads();
    if (t < 16) {                             // ty == 0 threads write 64 cols
      for (int ci = 0; ci < 4; ++ci) {
        float s = cred[1][0][tx][ci] + cred[1][1][tx][ci] +
                  cred[1][2][tx][ci] + cred[1][3][tx][ci];
        const int gcol = cb + tx + 16 * ci;
        mPart[(size_t)gcol * 32 + I] = M[ci];
        sPart[(size_t)gcol * 32 + I] = s;
      }
    }
  }
}

// ---------------------------------------------------------------------------
// Kernel 3: combine 32 partials per row -> lse; positive dot; mean via atomic.
// One wave per row (4 rows / block); block-level LDS reduce -> 1 atomic/block.
// ---------------------------------------------------------------------------
__global__ __launch_bounds__(256) void k_finish(const float* __restrict__ z,
                                                const float* __restrict__ mPart,
                                                const float* __restrict__ sPart,
                                                float* __restrict__ out) {
  __shared__ float red[4];
  const int t = threadIdx.x;
  const int wid = t >> 6, lane = t & 63;
  const int row = blockIdx.x * 4 + wid;

  float m = (lane < 32) ? mPart[(size_t)row * 32 + lane] : -INFINITY;
  float s = (lane < 32) ? sPart[(size_t)row * 32 + lane] : 0.0f;
  float M = m;
  for (int off = 1; off < 64; off <<= 1) M = fmaxf(M, __shfl_xor(M, off, 64));
  float se = (lane < 32) ? s * __expf(m - M) : 0.0f;
  for (int off = 1; off < 64; off <<= 1) se += __shfl_xor(se, off, 64);
  float lse = M + logf(se);

  const int partner = row < 1024 ? row + 1024 : row - 1024;
  float4 a = ((const float4*)(z + (size_t)row * 256))[lane];
  float4 b = ((const float4*)(z + (size_t)partner * 256))[lane];
  float d = a.x * b.x + a.y * b.y + a.z * b.z + a.w * b.w;
  for (int off = 1; off < 64; off <<= 1) d += __shfl_xor(d, off, 64);

  if (lane == 0) red[wid] = lse - d * INV_T;
  __syncthreads();
  if (t == 0)
    atomicAdd(out, (red[0] + red[1] + red[2] + red[3]) * (1.0f / 2048.0f));
}

// ---------------------------------------------------------------------------
extern "C" void kernel_launch(void* const* d_in, const int* in_sizes, int n_in,
                              void* d_out, int out_size, void* d_ws, size_t ws_size,
                              hipStream_t stream) {
  const float* rep  = (const float*)d_in[0];
  const int*   lens = (const int*)  d_in[1];
  const float* W    = (const float*)d_in[2];
  const float* bias = (const float*)d_in[3];
  float* out = (float*)d_out;

  float* z     = (float*)d_ws;            // 2048*256 f32 = 2 MB
  float* mPart = z + NROWS * PDIM;        // 2048*32 f32
  float* sPart = mPart + NROWS * 32;      // 2048*32 f32

  k_proj  <<<256, 512, 0, stream>>>(rep, lens, W, bias, z, out);
  k_gram  <<<528, 256, 0, stream>>>(z, mPart, sPart);
  k_finish<<<512, 256, 0, stream>>>(z, mPart, sPart, out);
}